// Round 1
// 338.756 us; speedup vs baseline: 1.0601x; 1.0601x over previous
//
#include <hip/hip_runtime.h>
#include <hip/hip_bf16.h>

// GCN encoder: 3 layers on N=100000 nodes, E=1250000 edges, 64 features.
// gcn(x) = relu(D^-1/2 (A+I) D^-1/2 (xW) + b)
// Folding: hs = dinv .* (xW);  agg[d] = hs[d] + sum_{s->d} hs[s];
//          next layer's GEMM applies relu(dinv[d]*agg + b) as its pre-transform.
// R1: dst-CSR + gather segmented reduction (no fp32 atomics).
// R2: hierarchical scan.  R3: bucketed 2-phase CSR build.
// R4: bf16 hs, histogram-free slab build, b128 gemm k-loop.
// R5: aggregate was latency-bound (VALU 32%, HBM 23%): half-wave uint(bf16x2)
//     gathers, 8 edges in flight/wave, shfl-broadcast prefetched indices.
//     partition: LDS-staged bucket-ordered output (coalesced store runs).
//     csr_local: 1024 threads (was 196 blocks x 256 = latency-serial).
// R6: aggregate still issue/latency-bound (VALU 30%, HBM 22%, no pipe
//     saturated): quarter-wave uint2 (8B/lane) gathers -> 1 load instr per
//     4 edges (was 2), 16 edges in flight/wave (was 8), ~half the VALU per
//     edge. Combine via shfl_xor(16/32) butterfly; 16-lane float4 store.

#define WG 256
#define BSHIFT 9                 // 512 nodes per bucket
#define BSIZE  (1 << BSHIFT)
#define BCAP   8192              // pair slots per bucket (mean 6400, sd ~80)
#define PCHUNK 2048              // edges per partition block (8 per thread)
#define XS_LD  68                // xs leading dim: 16B-aligned rows, b128 reads

// cur2[b] = b*BCAP  (write cursor into bucket slab)
__global__ __launch_bounds__(WG) void bcur_init(int* __restrict__ cur2, int nbk) {
    int b = threadIdx.x;
    if (b < nbk) cur2[b] = b * BCAP;
}

// Partition edges by dst-bucket into packed pairs ((dst&511)<<32 | src) in
// fixed per-bucket slabs. LDS histogram -> one global atomic per touched
// bucket -> stage (pair,dest) in LDS in bucket-slot order -> linear output
// loop: consecutive threads write consecutive dests within a bucket run.
__global__ __launch_bounds__(WG) void partition(const int* __restrict__ ei,
                                                int* __restrict__ cur2,
                                                unsigned long long* __restrict__ pairs,
                                                int E) {
    __shared__ int hist[256];
    __shared__ int gbase[256];
    __shared__ int lb[256];
    __shared__ int sums[WG];
    __shared__ unsigned long long sp[PCHUNK];
    __shared__ int sd[PCHUNK];
    const int t = threadIdx.x;
    const int base = blockIdx.x * PCHUNK;
    const int total = min(PCHUNK, E - base);

    hist[t] = 0;
    __syncthreads();

    int s[8], d[8], r[8];
#pragma unroll
    for (int i = 0; i < 8; i++) {
        int e = base + i * WG + t;           // coalesced
        bool ok = e < E;
        s[i] = ok ? ei[e] : 0;
        d[i] = ok ? ei[E + e] : 0;
        r[i] = ok ? atomicAdd(&hist[d[i] >> BSHIFT], 1) : 0;
        if (!ok) d[i] = -1;
    }
    __syncthreads();

    int hv = hist[t];
    if (hv > 0) gbase[t] = atomicAdd(&cur2[t], hv);
    // exclusive scan of hist -> lb (local slot base per bucket)
    sums[t] = hv;
    __syncthreads();
    for (int ofs = 1; ofs < WG; ofs <<= 1) {
        int u = (t >= ofs) ? sums[t - ofs] : 0;
        __syncthreads();
        sums[t] += u;
        __syncthreads();
    }
    lb[t] = sums[t] - hv;
    __syncthreads();

#pragma unroll
    for (int i = 0; i < 8; i++) {
        if (d[i] >= 0) {
            int b = d[i] >> BSHIFT;
            int slot = lb[b] + r[i];
            sp[slot] = ((unsigned long long)(unsigned)(d[i] & (BSIZE - 1)) << 32) |
                       (unsigned)s[i];
            sd[slot] = gbase[b] + r[i];
        }
    }
    __syncthreads();

    for (int j = t; j < total; j += WG)
        pairs[sd[j]] = sp[j];
}

// Scan bucket totals (cur2[b]-b*BCAP) -> bbase[b] (exclusive); off[N] = E.
__global__ __launch_bounds__(WG) void bsum_scan(const int* __restrict__ cur2,
                                                int* __restrict__ bbase, int nbk,
                                                int* __restrict__ off, int N) {
    __shared__ int sums[WG];
    const int t = threadIdx.x;
    int s = (t < nbk) ? (cur2[t] - t * BCAP) : 0;
    sums[t] = s;
    __syncthreads();
    for (int ofs = 1; ofs < WG; ofs <<= 1) {
        int u = (t >= ofs) ? sums[t - ofs] : 0;
        __syncthreads();
        sums[t] += u;
        __syncthreads();
    }
    if (t < nbk) bbase[t] = sums[t] - s;
    if (t == WG - 1) off[N] = sums[WG - 1];
}

// Per-bucket: LDS histogram over 512 local nodes -> LDS scan -> off/dinv/cursors
// -> fill private csr window. 1024 threads (only 196 blocks exist).
__global__ __launch_bounds__(1024) void csr_local(const unsigned long long* __restrict__ pairs,
                                                  const int* __restrict__ cur2,
                                                  const int* __restrict__ bbase,
                                                  int* __restrict__ off,
                                                  float* __restrict__ dinv,
                                                  int* __restrict__ csr, int N) {
    __shared__ int h[BSIZE];
    __shared__ int cur[BSIZE];
    __shared__ int sums[1024];
    const int b = blockIdx.x;
    const int t = threadIdx.x;
    const int node0 = b << BSHIFT;
    const int nlocal = min(BSIZE, N - node0);
    const int pstart = b * BCAP;
    const int pend = cur2[b];
    const int base = bbase[b];

    if (t < BSIZE) h[t] = 0;
    __syncthreads();

    for (int e = pstart + t; e < pend; e += 1024)
        atomicAdd(&h[(int)(pairs[e] >> 32)], 1);
    __syncthreads();

    // inclusive scan over 1024 slots (only first BSIZE carry data)
    int s = (t < BSIZE) ? h[t] : 0;
    sums[t] = s;
    __syncthreads();
    for (int ofs = 1; ofs < 1024; ofs <<= 1) {
        int u = (t >= ofs) ? sums[t - ofs] : 0;
        __syncthreads();
        sums[t] += u;
        __syncthreads();
    }
    if (t < nlocal) {
        int run = base + sums[t] - s;
        off[node0 + t] = run;
        cur[t] = run;
        dinv[node0 + t] = rsqrtf((float)(s + 1));
    }
    __syncthreads();

    for (int e = pstart + t; e < pend; e += 1024) {
        unsigned long long p = pairs[e];
        int local = (int)(p >> 32);
        int src = (int)(p & 0xffffffffu);
        int pos = atomicAdd(&cur[local], 1);
        csr[pos] = src;
    }
}

// Fused GEMM: out = post( pre(in) @ W )
//   pre(v)  = pre_flag ? relu(dinv[row]*v + b_pre[col]) : v
//   post(a) = (post_scale ? dinv[row]*a : a) + (b_post ? b_post[col] : 0)
__global__ __launch_bounds__(WG) void gemm_fused(
    const float* __restrict__ in, const float* __restrict__ W,
    const float* __restrict__ dinv, const float* __restrict__ b_pre, int pre_flag,
    int post_scale, const float* __restrict__ b_post,
    void* __restrict__ out1, int out_bf16, int n_rows)
{
    __shared__ float Ws[64 * 64];
    __shared__ float xs[64 * XS_LD];

    const int t = threadIdx.x;
    const int row0 = blockIdx.x * 64;

    const float4* W4 = (const float4*)W;
    float4* Ws4 = (float4*)Ws;
#pragma unroll
    for (int i = 0; i < 4; i++) Ws4[i * WG + t] = W4[i * WG + t];

#pragma unroll
    for (int i = 0; i < 4; i++) {
        int j = i * WG + t;
        int rr = j >> 4;
        int c  = (j & 15) * 4;
        int row = row0 + rr;
        float4 v = make_float4(0.f, 0.f, 0.f, 0.f);
        if (row < n_rows) {
            v = *(const float4*)(in + (size_t)row * 64 + c);
            if (pre_flag) {
                float dv = dinv[row];
                float4 bb = *(const float4*)(b_pre + c);
                v.x = fmaxf(fmaf(dv, v.x, bb.x), 0.f);
                v.y = fmaxf(fmaf(dv, v.y, bb.y), 0.f);
                v.z = fmaxf(fmaf(dv, v.z, bb.z), 0.f);
                v.w = fmaxf(fmaf(dv, v.w, bb.w), 0.f);
            }
        }
        float* xp = xs + rr * XS_LD + c;
        xp[0] = v.x; xp[1] = v.y; xp[2] = v.z; xp[3] = v.w;
    }
    __syncthreads();

    const int fg = (t & 15) * 4;
    const int r0 = (t >> 4) * 4;
    float acc[4][4] = {};

#pragma unroll
    for (int kq = 0; kq < 64; kq += 4) {          // k-quads: b128 xs reads
        float4 xr[4];
#pragma unroll
        for (int r = 0; r < 4; r++)
            xr[r] = *(const float4*)(xs + (r0 + r) * XS_LD + kq);
#pragma unroll
        for (int kk = 0; kk < 4; kk++) {
            float4 wv = *(const float4*)(Ws + (kq + kk) * 64 + fg);
#pragma unroll
            for (int r = 0; r < 4; r++) {
                float xv = ((const float*)&xr[r])[kk];
                acc[r][0] = fmaf(xv, wv.x, acc[r][0]);
                acc[r][1] = fmaf(xv, wv.y, acc[r][1]);
                acc[r][2] = fmaf(xv, wv.z, acc[r][2]);
                acc[r][3] = fmaf(xv, wv.w, acc[r][3]);
            }
        }
    }

    float4 bp = b_post ? *(const float4*)(b_post + fg) : make_float4(0.f, 0.f, 0.f, 0.f);
#pragma unroll
    for (int r = 0; r < 4; r++) {
        int row = row0 + r0 + r;
        if (row >= n_rows) break;
        float sc = post_scale ? dinv[row] : 1.0f;
        float4 o;
        o.x = fmaf(acc[r][0], sc, bp.x);
        o.y = fmaf(acc[r][1], sc, bp.y);
        o.z = fmaf(acc[r][2], sc, bp.z);
        o.w = fmaf(acc[r][3], sc, bp.w);
        if (out_bf16) {
            union { __hip_bfloat16 h[4]; ushort4 u; } pk;
            pk.h[0] = __float2bfloat16(o.x);
            pk.h[1] = __float2bfloat16(o.y);
            pk.h[2] = __float2bfloat16(o.z);
            pk.h[3] = __float2bfloat16(o.w);
            *(ushort4*)((unsigned short*)out1 + ((size_t)row << 6) + fg) = pk.u;
        } else {
            *(float4*)((float*)out1 + ((size_t)row << 6) + fg) = o;
        }
    }
}

__device__ __forceinline__ void acc_bf16x2(float& a, float& b, unsigned u) {
    union { unsigned v; float f; } lo, hi;
    lo.v = u << 16;
    hi.v = u & 0xffff0000u;
    a += lo.f;
    b += hi.f;
}

// Segmented reduction over dst-CSR: B[d] = A[d] + sum A[csr[e]]  (A is bf16).
// One wave per node. Lane l reads uint2 (4 bf16) at col c = l&15; quarter-wave
// g = l>>4 processes different edges: one load instr covers 4 edges, k-unroll 4
// puts 16 edges in flight/wave. Indices prefetched 64-at-a-time (coalesced)
// and broadcast via shfl. Combine quarters with shfl_xor(16/32) butterfly;
// lanes 0-15 store float4 (256B coalesced per node).
__global__ __launch_bounds__(WG) void aggregate(
    const uint2* __restrict__ A4, float* __restrict__ B,
    const int* __restrict__ off, const int* __restrict__ csr, int N)
{
    int node = blockIdx.x * 4 + (threadIdx.x >> 6);
    if (node >= N) return;
    const int l = threadIdx.x & 63;
    const int c = l & 15;           // uint2 col (4 bf16 values)
    const int g = l >> 4;           // quarter-wave

    const int s0 = off[node];
    const int s1 = off[node + 1];

    float4 acc = make_float4(0.f, 0.f, 0.f, 0.f);
    if (g == 0) {                   // self-loop once
        uint2 v = A4[((size_t)node << 4) + c];
        acc_bf16x2(acc.x, acc.y, v.x);
        acc_bf16x2(acc.z, acc.w, v.y);
    }

    for (int p = s0; p < s1; p += 64) {
        int cnt = min(64, s1 - p);
        int idx = (l < cnt) ? csr[p + l] : 0;      // coalesced prefetch
        for (int j = 0; j < cnt; j += 16) {
#pragma unroll
            for (int k = 0; k < 4; k++) {
                int e = j + 4 * g + k;             // <= 63 by construction
                int src = __shfl(idx, e);          // uniform control, all lanes
                if (e < cnt) {
                    uint2 v = A4[((size_t)src << 4) + c];
                    acc_bf16x2(acc.x, acc.y, v.x);
                    acc_bf16x2(acc.z, acc.w, v.y);
                }
            }
        }
    }

    // combine quarter-waves: butterfly over lane bits 4,5
    acc.x += __shfl_xor(acc.x, 16);
    acc.y += __shfl_xor(acc.y, 16);
    acc.z += __shfl_xor(acc.z, 16);
    acc.w += __shfl_xor(acc.w, 16);
    acc.x += __shfl_xor(acc.x, 32);
    acc.y += __shfl_xor(acc.y, 32);
    acc.z += __shfl_xor(acc.z, 32);
    acc.w += __shfl_xor(acc.w, 32);
    if (g == 0)
        *(float4*)(B + ((size_t)node << 6) + 4 * c) = acc;   // 256B coalesced
}

extern "C" void kernel_launch(void* const* d_in, const int* in_sizes, int n_in,
                              void* d_out, int out_size, void* d_ws, size_t ws_size,
                              hipStream_t stream) {
    const float* x  = (const float*)d_in[0];
    const int*   ei = (const int*)d_in[1];
    const float* W1 = (const float*)d_in[2];
    const float* b1 = (const float*)d_in[3];
    const float* W2 = (const float*)d_in[4];
    const float* b2 = (const float*)d_in[5];
    const float* W3 = (const float*)d_in[6];
    const float* b3 = (const float*)d_in[7];
    float* out = (float*)d_out;

    const int N = in_sizes[0] / 64;    // 100000
    const int E = in_sizes[1] / 2;     // 1250000
    const int nbk = (N + BSIZE - 1) / BSIZE;        // 196 buckets

    // workspace layout
    int*   off  = (int*)d_ws;                       // N+1
    int*   csr  = off + (N + 1);                    // E
    int*   cur2 = csr + E;                          // 256
    int*   bbase= cur2 + 256;                       // 256
    uintptr_t pa = (uintptr_t)(bbase + 256);
    pa = (pa + 255) & ~(uintptr_t)255;
    float* dinv = (float*)pa;                       // N
    __hip_bfloat16* A = (__hip_bfloat16*)(dinv + N);// N*64 bf16 (hs)
    float* B    = (float*)(A + (size_t)N * 64);     // N*64 fp32 (agg)
    unsigned long long* pairs = (unsigned long long*)B;  // aliased: dead until agg1
                                                    // nbk*BCAP*8 = 12.9MB <= 25.6MB

    const int gG = (N + 63) / 64;
    const int gA = (N + 3) / 4;
    const int gP = (E + PCHUNK - 1) / PCHUNK;

    // CSR build (per call; ws re-poisoned every launch)
    bcur_init<<<1,   WG, 0, stream>>>(cur2, nbk);
    partition<<<gP,  WG, 0, stream>>>(ei, cur2, pairs, E);
    bsum_scan<<<1,   WG, 0, stream>>>(cur2, bbase, nbk, off, N);
    csr_local<<<nbk, 1024, 0, stream>>>(pairs, cur2, bbase, off, dinv, csr, N);

    // Layer 1: A = bf16(dinv.*(x@W1)); B = A[d] + sum A[src]
    gemm_fused<<<gG, WG, 0, stream>>>(x, W1, dinv, nullptr, 0, 1, nullptr, A, 1, N);
    aggregate <<<gA, WG, 0, stream>>>((const uint2*)A, B, off, csr, N);

    // Layer 2: in = B (pre: relu(dinv*v + b1)); A = bf16(dinv.*(h@W2)); B = agg
    gemm_fused<<<gG, WG, 0, stream>>>(B, W2, dinv, b1, 1, 1, nullptr, A, 1, N);
    aggregate <<<gA, WG, 0, stream>>>((const uint2*)A, B, off, csr, N);

    // Layer 3: in = B (pre: relu(dinv*v + b2)); out = h@W3 + b3 (fp32)
    gemm_fused<<<gG, WG, 0, stream>>>(B, W3, dinv, b2, 1, 0, b3, out, 0, N);
}

// Round 2
// 253.357 us; speedup vs baseline: 1.4174x; 1.3371x over previous
//
#include <hip/hip_runtime.h>
#include <hip/hip_bf16.h>

// GCN encoder: 3 layers on N=100000 nodes, E=1250000 edges, 64 features.
// gcn(x) = relu(D^-1/2 (A+I) D^-1/2 (xW) + b)
// Folding: hs = dinv .* (xW);  agg[d] = hs[d] + sum_{s->d} hs[s];
//          next layer's GEMM applies relu(dinv[d]*agg + b) as its pre-transform.
// R1: dst-CSR + gather segmented reduction (no fp32 atomics).
// R2: hierarchical scan.  R3: bucketed 2-phase CSR build.
// R4: bf16 hs, histogram-free slab build, b128 gemm k-loop.
// R5: aggregate half-wave uint gathers; LDS-staged partition; 1024t csr_local.
// R6: aggregate quarter-wave uint2 gathers, 16 edges in flight/wave.
// R7: gemm_fused was latency-bound (VGPR=256 -> 8.5% occupancy, VALU 24%,
//     HBM 8%; vector-FMA floor ~15us vs 48 measured). Rewritten on MFMA:
//     split fp32 = bf16_hi + bf16_lo for both operands, 4 products on
//     v_mfma_f32_16x16x32_bf16 with fp32 accum => fp32-level accuracy
//     (err ~2^-18 rel, invisible under the existing 2^-9 bf16 hs rounding).
//     W staged transposed in LDS (hi/lo, LD=72: b128 frag reads hit all 32
//     banks evenly), A-frags straight from global, pre-transform in fp32.
//     32 MFMAs/wave replace 1024 VALU FMAs/thread.

#define WG 256
#define BSHIFT 9                 // 512 nodes per bucket
#define BSIZE  (1 << BSHIFT)
#define BCAP   8192              // pair slots per bucket (mean 6400, sd ~80)
#define PCHUNK 2048              // edges per partition block (8 per thread)
#define WT_LD  72                // transposed-W LDS leading dim (bf16 elems):
                                 // 144B row stride -> even 32-bank coverage,
                                 // 16B-aligned b128 fragment reads

typedef __attribute__((ext_vector_type(8))) short bf16x8;
typedef __attribute__((ext_vector_type(4))) float f32x4;

__device__ __forceinline__ unsigned short f2bf(float f) {
    union { float f; unsigned u; } v; v.f = f;
    unsigned r = v.u + 0x7fffu + ((v.u >> 16) & 1u);   // RNE
    return (unsigned short)(r >> 16);
}
__device__ __forceinline__ float bf2f(unsigned short h) {
    union { unsigned u; float f; } v; v.u = ((unsigned)h) << 16;
    return v.f;
}

// cur2[b] = b*BCAP  (write cursor into bucket slab)
__global__ __launch_bounds__(WG) void bcur_init(int* __restrict__ cur2, int nbk) {
    int b = threadIdx.x;
    if (b < nbk) cur2[b] = b * BCAP;
}

// Partition edges by dst-bucket into packed pairs ((dst&511)<<32 | src) in
// fixed per-bucket slabs. LDS histogram -> one global atomic per touched
// bucket -> stage (pair,dest) in LDS in bucket-slot order -> linear output
// loop: consecutive threads write consecutive dests within a bucket run.
__global__ __launch_bounds__(WG) void partition(const int* __restrict__ ei,
                                                int* __restrict__ cur2,
                                                unsigned long long* __restrict__ pairs,
                                                int E) {
    __shared__ int hist[256];
    __shared__ int gbase[256];
    __shared__ int lb[256];
    __shared__ int sums[WG];
    __shared__ unsigned long long sp[PCHUNK];
    __shared__ int sd[PCHUNK];
    const int t = threadIdx.x;
    const int base = blockIdx.x * PCHUNK;
    const int total = min(PCHUNK, E - base);

    hist[t] = 0;
    __syncthreads();

    int s[8], d[8], r[8];
#pragma unroll
    for (int i = 0; i < 8; i++) {
        int e = base + i * WG + t;           // coalesced
        bool ok = e < E;
        s[i] = ok ? ei[e] : 0;
        d[i] = ok ? ei[E + e] : 0;
        r[i] = ok ? atomicAdd(&hist[d[i] >> BSHIFT], 1) : 0;
        if (!ok) d[i] = -1;
    }
    __syncthreads();

    int hv = hist[t];
    if (hv > 0) gbase[t] = atomicAdd(&cur2[t], hv);
    // exclusive scan of hist -> lb (local slot base per bucket)
    sums[t] = hv;
    __syncthreads();
    for (int ofs = 1; ofs < WG; ofs <<= 1) {
        int u = (t >= ofs) ? sums[t - ofs] : 0;
        __syncthreads();
        sums[t] += u;
        __syncthreads();
    }
    lb[t] = sums[t] - hv;
    __syncthreads();

#pragma unroll
    for (int i = 0; i < 8; i++) {
        if (d[i] >= 0) {
            int b = d[i] >> BSHIFT;
            int slot = lb[b] + r[i];
            sp[slot] = ((unsigned long long)(unsigned)(d[i] & (BSIZE - 1)) << 32) |
                       (unsigned)s[i];
            sd[slot] = gbase[b] + r[i];
        }
    }
    __syncthreads();

    for (int j = t; j < total; j += WG)
        pairs[sd[j]] = sp[j];
}

// Scan bucket totals (cur2[b]-b*BCAP) -> bbase[b] (exclusive); off[N] = E.
__global__ __launch_bounds__(WG) void bsum_scan(const int* __restrict__ cur2,
                                                int* __restrict__ bbase, int nbk,
                                                int* __restrict__ off, int N) {
    __shared__ int sums[WG];
    const int t = threadIdx.x;
    int s = (t < nbk) ? (cur2[t] - t * BCAP) : 0;
    sums[t] = s;
    __syncthreads();
    for (int ofs = 1; ofs < WG; ofs <<= 1) {
        int u = (t >= ofs) ? sums[t - ofs] : 0;
        __syncthreads();
        sums[t] += u;
        __syncthreads();
    }
    if (t < nbk) bbase[t] = sums[t] - s;
    if (t == WG - 1) off[N] = sums[WG - 1];
}

// Per-bucket: LDS histogram over 512 local nodes -> LDS scan -> off/dinv/cursors
// -> fill private csr window. 1024 threads (only 196 blocks exist).
__global__ __launch_bounds__(1024) void csr_local(const unsigned long long* __restrict__ pairs,
                                                  const int* __restrict__ cur2,
                                                  const int* __restrict__ bbase,
                                                  int* __restrict__ off,
                                                  float* __restrict__ dinv,
                                                  int* __restrict__ csr, int N) {
    __shared__ int h[BSIZE];
    __shared__ int cur[BSIZE];
    __shared__ int sums[1024];
    const int b = blockIdx.x;
    const int t = threadIdx.x;
    const int node0 = b << BSHIFT;
    const int nlocal = min(BSIZE, N - node0);
    const int pstart = b * BCAP;
    const int pend = cur2[b];
    const int base = bbase[b];

    if (t < BSIZE) h[t] = 0;
    __syncthreads();

    for (int e = pstart + t; e < pend; e += 1024)
        atomicAdd(&h[(int)(pairs[e] >> 32)], 1);
    __syncthreads();

    // inclusive scan over 1024 slots (only first BSIZE carry data)
    int s = (t < BSIZE) ? h[t] : 0;
    sums[t] = s;
    __syncthreads();
    for (int ofs = 1; ofs < 1024; ofs <<= 1) {
        int u = (t >= ofs) ? sums[t - ofs] : 0;
        __syncthreads();
        sums[t] += u;
        __syncthreads();
    }
    if (t < nlocal) {
        int run = base + sums[t] - s;
        off[node0 + t] = run;
        cur[t] = run;
        dinv[node0 + t] = rsqrtf((float)(s + 1));
    }
    __syncthreads();

    for (int e = pstart + t; e < pend; e += 1024) {
        unsigned long long p = pairs[e];
        int local = (int)(p >> 32);
        int src = (int)(p & 0xffffffffu);
        int pos = atomicAdd(&cur[local], 1);
        csr[pos] = src;
    }
}

// Fused GEMM via split-bf16 MFMA: out = post( pre(in) @ W )
//   pre(v)  = pre_flag ? relu(dinv[row]*v + b_pre[col]) : v
//   post(a) = (post_scale ? dinv[row]*a : a) + (b_post ? b_post[col] : 0)
// Block = 64 rows x 64 cols, 4 waves x 16 rows. Per wave:
//   A-frags: lane reads in[row0+(l&15)][kc*32+(l>>4)*8 ..+7] from global,
//            pre-transform in fp32, split to bf16 hi/lo (x = xh + xl).
//   B-frags: W staged transposed hi/lo in LDS; lane b128-reads
//            Wt[ct*16+(l&15)][kc*32+(l>>4)*8 ..+7].
//   acc[ct] += xh*wh + xl*wh + xh*wl + xl*wl  (4 MFMAs per (ct,kc))
//   => fp32-accurate GEMM at matrix-core rate.
__global__ __launch_bounds__(WG, 4) void gemm_fused(
    const float* __restrict__ in, const float* __restrict__ W,
    const float* __restrict__ dinv, const float* __restrict__ b_pre, int pre_flag,
    int post_scale, const float* __restrict__ b_post,
    void* __restrict__ out1, int out_bf16, int n_rows)
{
    __shared__ __align__(16) short Wh[64 * WT_LD];
    __shared__ __align__(16) short Wl[64 * WT_LD];

    const int t = threadIdx.x;

    // stage W transposed, split hi/lo bf16 (Wt[j][k], j = output col)
    const float4* W4 = (const float4*)W;
#pragma unroll
    for (int i = 0; i < 4; i++) {
        int q = i * WG + t;              // float4 index, 1024 total
        float4 w = W4[q];
        int base = q * 4;
        int k = base >> 6;
        int j0 = base & 63;
        float wf[4] = {w.x, w.y, w.z, w.w};
#pragma unroll
        for (int e = 0; e < 4; e++) {
            unsigned short h = f2bf(wf[e]);
            Wh[(j0 + e) * WT_LD + k] = (short)h;
            Wl[(j0 + e) * WT_LD + k] = (short)f2bf(wf[e] - bf2f(h));
        }
    }

    const int wid = t >> 6;              // wave 0..3
    const int l = t & 63;
    const int lr = l & 15;
    const int lk = l >> 4;
    const int row0 = blockIdx.x * 64 + wid * 16;
    const int arow = row0 + lr;
    const int srow = (arow < n_rows) ? arow : 0;   // safe row for loads

    // A fragments: 2 k-chunks of 32, pre-transform + hi/lo split
    bf16x8 ah[2], al[2];
    float dv = pre_flag ? dinv[srow] : 0.f;
#pragma unroll
    for (int kc = 0; kc < 2; kc++) {
        const float* p = in + (size_t)srow * 64 + kc * 32 + lk * 8;
        float4 v0 = *(const float4*)p;
        float4 v1 = *(const float4*)(p + 4);
        float vv[8] = {v0.x, v0.y, v0.z, v0.w, v1.x, v1.y, v1.z, v1.w};
        if (pre_flag) {
            const float* bp = b_pre + kc * 32 + lk * 8;
            float4 b0 = *(const float4*)bp;
            float4 b1 = *(const float4*)(bp + 4);
            float bb[8] = {b0.x, b0.y, b0.z, b0.w, b1.x, b1.y, b1.z, b1.w};
#pragma unroll
            for (int e = 0; e < 8; e++)
                vv[e] = fmaxf(fmaf(dv, vv[e], bb[e]), 0.f);
        }
#pragma unroll
        for (int e = 0; e < 8; e++) {
            unsigned short h = f2bf(vv[e]);
            ah[kc][e] = (short)h;
            al[kc][e] = (short)f2bf(vv[e] - bf2f(h));
        }
    }

    __syncthreads();

    f32x4 acc[4] = {};
#pragma unroll
    for (int ct = 0; ct < 4; ct++) {
#pragma unroll
        for (int kc = 0; kc < 2; kc++) {
            const short* ph = &Wh[(ct * 16 + lr) * WT_LD + kc * 32 + lk * 8];
            const short* pl = &Wl[(ct * 16 + lr) * WT_LD + kc * 32 + lk * 8];
            bf16x8 bh = *(const bf16x8*)ph;
            bf16x8 bl = *(const bf16x8*)pl;
            acc[ct] = __builtin_amdgcn_mfma_f32_16x16x32_bf16(ah[kc], bh, acc[ct], 0, 0, 0);
            acc[ct] = __builtin_amdgcn_mfma_f32_16x16x32_bf16(al[kc], bh, acc[ct], 0, 0, 0);
            acc[ct] = __builtin_amdgcn_mfma_f32_16x16x32_bf16(ah[kc], bl, acc[ct], 0, 0, 0);
            acc[ct] = __builtin_amdgcn_mfma_f32_16x16x32_bf16(al[kc], bl, acc[ct], 0, 0, 0);
        }
    }

    // store: D[row = row0 + lk*4 + r][col = ct*16 + lr]  (m89-verified C/D map)
#pragma unroll
    for (int r = 0; r < 4; r++) {
        int orow = row0 + lk * 4 + r;
        if (orow >= n_rows) continue;
        float sc = post_scale ? dinv[orow] : 1.0f;
#pragma unroll
        for (int ct = 0; ct < 4; ct++) {
            float bpv = b_post ? b_post[ct * 16 + lr] : 0.f;
            float o = fmaf(acc[ct][r], sc, bpv);
            if (out_bf16)
                ((unsigned short*)out1)[((size_t)orow << 6) + ct * 16 + lr] = f2bf(o);
            else
                ((float*)out1)[((size_t)orow << 6) + ct * 16 + lr] = o;
        }
    }
}

__device__ __forceinline__ void acc_bf16x2(float& a, float& b, unsigned u) {
    union { unsigned v; float f; } lo, hi;
    lo.v = u << 16;
    hi.v = u & 0xffff0000u;
    a += lo.f;
    b += hi.f;
}

// Segmented reduction over dst-CSR: B[d] = A[d] + sum A[csr[e]]  (A is bf16).
// One wave per node. Lane l reads uint2 (4 bf16) at col c = l&15; quarter-wave
// g = l>>4 processes different edges: one load instr covers 4 edges, k-unroll 4
// puts 16 edges in flight/wave. Indices prefetched 64-at-a-time (coalesced)
// and broadcast via shfl. Combine quarters with shfl_xor(16/32) butterfly;
// lanes 0-15 store float4 (256B coalesced per node).
__global__ __launch_bounds__(WG) void aggregate(
    const uint2* __restrict__ A4, float* __restrict__ B,
    const int* __restrict__ off, const int* __restrict__ csr, int N)
{
    int node = blockIdx.x * 4 + (threadIdx.x >> 6);
    if (node >= N) return;
    const int l = threadIdx.x & 63;
    const int c = l & 15;           // uint2 col (4 bf16 values)
    const int g = l >> 4;           // quarter-wave

    const int s0 = off[node];
    const int s1 = off[node + 1];

    float4 acc = make_float4(0.f, 0.f, 0.f, 0.f);
    if (g == 0) {                   // self-loop once
        uint2 v = A4[((size_t)node << 4) + c];
        acc_bf16x2(acc.x, acc.y, v.x);
        acc_bf16x2(acc.z, acc.w, v.y);
    }

    for (int p = s0; p < s1; p += 64) {
        int cnt = min(64, s1 - p);
        int idx = (l < cnt) ? csr[p + l] : 0;      // coalesced prefetch
        for (int j = 0; j < cnt; j += 16) {
#pragma unroll
            for (int k = 0; k < 4; k++) {
                int e = j + 4 * g + k;             // <= 63 by construction
                int src = __shfl(idx, e);          // uniform control, all lanes
                if (e < cnt) {
                    uint2 v = A4[((size_t)src << 4) + c];
                    acc_bf16x2(acc.x, acc.y, v.x);
                    acc_bf16x2(acc.z, acc.w, v.y);
                }
            }
        }
    }

    // combine quarter-waves: butterfly over lane bits 4,5
    acc.x += __shfl_xor(acc.x, 16);
    acc.y += __shfl_xor(acc.y, 16);
    acc.z += __shfl_xor(acc.z, 16);
    acc.w += __shfl_xor(acc.w, 16);
    acc.x += __shfl_xor(acc.x, 32);
    acc.y += __shfl_xor(acc.y, 32);
    acc.z += __shfl_xor(acc.z, 32);
    acc.w += __shfl_xor(acc.w, 32);
    if (g == 0)
        *(float4*)(B + ((size_t)node << 6) + 4 * c) = acc;   // 256B coalesced
}

extern "C" void kernel_launch(void* const* d_in, const int* in_sizes, int n_in,
                              void* d_out, int out_size, void* d_ws, size_t ws_size,
                              hipStream_t stream) {
    const float* x  = (const float*)d_in[0];
    const int*   ei = (const int*)d_in[1];
    const float* W1 = (const float*)d_in[2];
    const float* b1 = (const float*)d_in[3];
    const float* W2 = (const float*)d_in[4];
    const float* b2 = (const float*)d_in[5];
    const float* W3 = (const float*)d_in[6];
    const float* b3 = (const float*)d_in[7];
    float* out = (float*)d_out;

    const int N = in_sizes[0] / 64;    // 100000
    const int E = in_sizes[1] / 2;     // 1250000
    const int nbk = (N + BSIZE - 1) / BSIZE;        // 196 buckets

    // workspace layout
    int*   off  = (int*)d_ws;                       // N+1
    int*   csr  = off + (N + 1);                    // E
    int*   cur2 = csr + E;                          // 256
    int*   bbase= cur2 + 256;                       // 256
    uintptr_t pa = (uintptr_t)(bbase + 256);
    pa = (pa + 255) & ~(uintptr_t)255;
    float* dinv = (float*)pa;                       // N
    __hip_bfloat16* A = (__hip_bfloat16*)(dinv + N);// N*64 bf16 (hs)
    float* B    = (float*)(A + (size_t)N * 64);     // N*64 fp32 (agg)
    unsigned long long* pairs = (unsigned long long*)B;  // aliased: dead until agg1
                                                    // nbk*BCAP*8 = 12.9MB <= 25.6MB

    const int gG = (N + 63) / 64;
    const int gA = (N + 3) / 4;
    const int gP = (E + PCHUNK - 1) / PCHUNK;

    // CSR build (per call; ws re-poisoned every launch)
    bcur_init<<<1,   WG, 0, stream>>>(cur2, nbk);
    partition<<<gP,  WG, 0, stream>>>(ei, cur2, pairs, E);
    bsum_scan<<<1,   WG, 0, stream>>>(cur2, bbase, nbk, off, N);
    csr_local<<<nbk, 1024, 0, stream>>>(pairs, cur2, bbase, off, dinv, csr, N);

    // Layer 1: A = bf16(dinv.*(x@W1)); B = A[d] + sum A[src]
    gemm_fused<<<gG, WG, 0, stream>>>(x, W1, dinv, nullptr, 0, 1, nullptr, A, 1, N);
    aggregate <<<gA, WG, 0, stream>>>((const uint2*)A, B, off, csr, N);

    // Layer 2: in = B (pre: relu(dinv*v + b1)); A = bf16(dinv.*(h@W2)); B = agg
    gemm_fused<<<gG, WG, 0, stream>>>(B, W2, dinv, b1, 1, 1, nullptr, A, 1, N);
    aggregate <<<gA, WG, 0, stream>>>((const uint2*)A, B, off, csr, N);

    // Layer 3: in = B (pre: relu(dinv*v + b2)); out = h@W3 + b3 (fp32)
    gemm_fused<<<gG, WG, 0, stream>>>(B, W3, dinv, b2, 1, 0, b3, out, 0, N);
}

// Round 3
// 232.831 us; speedup vs baseline: 1.5423x; 1.0882x over previous
//
#include <hip/hip_runtime.h>
#include <hip/hip_bf16.h>

// GCN encoder: 3 layers on N=100000 nodes, E=1250000 edges, 64 features.
// gcn(x) = relu(D^-1/2 (A+I) D^-1/2 (xW) + b)
// Folding: hs = dinv .* (xW);  agg[d] = hs[d] + sum_{s->d} hs[s];
//          next layer's GEMM applies relu(dinv[d]*agg + b) as its pre-transform.
// R1: dst-CSR + gather segmented reduction (no fp32 atomics).
// R2: hierarchical scan.  R3: bucketed 2-phase CSR build.
// R4: bf16 hs, histogram-free slab build, b128 gemm k-loop.
// R5: aggregate half-wave uint gathers; LDS-staged partition; 1024t csr_local.
// R6: aggregate quarter-wave uint2 gathers, 16 edges in flight/wave.
// R7: gemm_fused rewritten on split-bf16 MFMA (fp32-accurate, 4 mfma/tile).
// R8: aggregate ~47% of issue was per-node overhead (butterfly + 64-wide
//     prefetch for mean degree 12.5): now quarter-wave per node (16 lanes x
//     uint2 = full row), no cross-lane combine, 16-deep unrolled edge loop
//     -> 16 loads in flight/wave (4x MLP). csr_local: pairs+csr staged in
//     LDS (100KB), one global pairs read, coalesced csr write-out, shfl scan
//     (2 barriers, was 20). partition: shfl scan (2 barriers, was 16).

#define WG 256
#define BSHIFT 9                 // 512 nodes per bucket
#define BSIZE  (1 << BSHIFT)
#define BCAP   8192              // pair slots per bucket (mean 6400, sd ~80)
#define PCHUNK 2048              // edges per partition block (8 per thread)
#define WT_LD  72                // transposed-W LDS leading dim (bf16 elems):
                                 // 144B row stride -> even 32-bank coverage,
                                 // 16B-aligned b128 fragment reads

typedef __attribute__((ext_vector_type(8))) short bf16x8;
typedef __attribute__((ext_vector_type(4))) float f32x4;

__device__ __forceinline__ unsigned short f2bf(float f) {
    union { float f; unsigned u; } v; v.f = f;
    unsigned r = v.u + 0x7fffu + ((v.u >> 16) & 1u);   // RNE
    return (unsigned short)(r >> 16);
}
__device__ __forceinline__ float bf2f(unsigned short h) {
    union { unsigned u; float f; } v; v.u = ((unsigned)h) << 16;
    return v.f;
}

// cur2[b] = b*BCAP  (write cursor into bucket slab)
__global__ __launch_bounds__(WG) void bcur_init(int* __restrict__ cur2, int nbk) {
    int b = threadIdx.x;
    if (b < nbk) cur2[b] = b * BCAP;
}

// Partition edges by dst-bucket into packed pairs ((dst&511)<<32 | src) in
// fixed per-bucket slabs. LDS histogram -> one global atomic per touched
// bucket -> stage (pair,dest) in LDS in bucket-slot order -> linear output
// loop: consecutive threads write consecutive dests within a bucket run.
__global__ __launch_bounds__(WG) void partition(const int* __restrict__ ei,
                                                int* __restrict__ cur2,
                                                unsigned long long* __restrict__ pairs,
                                                int E) {
    __shared__ int hist[256];
    __shared__ int gbase[256];
    __shared__ int lb[256];
    __shared__ int wsum4[4];
    __shared__ unsigned long long sp[PCHUNK];
    __shared__ int sd[PCHUNK];
    const int t = threadIdx.x;
    const int lane = t & 63;
    const int w = t >> 6;
    const int base = blockIdx.x * PCHUNK;
    const int total = min(PCHUNK, E - base);

    hist[t] = 0;
    __syncthreads();

    int s[8], d[8], r[8];
#pragma unroll
    for (int i = 0; i < 8; i++) {
        int e = base + i * WG + t;           // coalesced
        bool ok = e < E;
        s[i] = ok ? ei[e] : 0;
        d[i] = ok ? ei[E + e] : 0;
        r[i] = ok ? atomicAdd(&hist[d[i] >> BSHIFT], 1) : 0;
        if (!ok) d[i] = -1;
    }
    __syncthreads();

    int hv = hist[t];
    if (hv > 0) gbase[t] = atomicAdd(&cur2[t], hv);
    // exclusive scan of hist -> lb: wave shfl scan + 4-wave fixup
    int sc = hv;
#pragma unroll
    for (int ofs = 1; ofs < 64; ofs <<= 1) {
        int u = __shfl_up(sc, ofs);
        if (lane >= ofs) sc += u;
    }
    if (lane == 63) wsum4[w] = sc;
    __syncthreads();
    if (t == 0) {
        int run = 0;
#pragma unroll
        for (int i = 0; i < 4; i++) { int x = wsum4[i]; wsum4[i] = run; run += x; }
    }
    __syncthreads();
    lb[t] = sc + wsum4[w] - hv;              // exclusive
    __syncthreads();

#pragma unroll
    for (int i = 0; i < 8; i++) {
        if (d[i] >= 0) {
            int b = d[i] >> BSHIFT;
            int slot = lb[b] + r[i];
            sp[slot] = ((unsigned long long)(unsigned)(d[i] & (BSIZE - 1)) << 32) |
                       (unsigned)s[i];
            sd[slot] = gbase[b] + r[i];
        }
    }
    __syncthreads();

    for (int j = t; j < total; j += WG)
        pairs[sd[j]] = sp[j];
}

// Scan bucket totals (cur2[b]-b*BCAP) -> bbase[b] (exclusive); off[N] = E.
__global__ __launch_bounds__(WG) void bsum_scan(const int* __restrict__ cur2,
                                                int* __restrict__ bbase, int nbk,
                                                int* __restrict__ off, int N) {
    __shared__ int sums[WG];
    const int t = threadIdx.x;
    int s = (t < nbk) ? (cur2[t] - t * BCAP) : 0;
    sums[t] = s;
    __syncthreads();
    for (int ofs = 1; ofs < WG; ofs <<= 1) {
        int u = (t >= ofs) ? sums[t - ofs] : 0;
        __syncthreads();
        sums[t] += u;
        __syncthreads();
    }
    if (t < nbk) bbase[t] = sums[t] - s;
    if (t == WG - 1) off[N] = sums[WG - 1];
}

// Per-bucket CSR: stage pairs (<=64KB) + bucket-local csr (32KB) in LDS.
// One global pairs read, LDS hist/scatter, shfl scan (2 barriers),
// fully-coalesced csr write-out. 196 blocks x 1024 threads, 100KB LDS.
__global__ __launch_bounds__(1024) void csr_local(const unsigned long long* __restrict__ pairs,
                                                  const int* __restrict__ cur2,
                                                  const int* __restrict__ bbase,
                                                  int* __restrict__ off,
                                                  float* __restrict__ dinv,
                                                  int* __restrict__ csr, int N) {
    __shared__ unsigned long long sp[BCAP];   // 64 KB staged pairs
    __shared__ int cs[BCAP];                  // 32 KB bucket-local csr
    __shared__ int h[BSIZE];
    __shared__ int cur[BSIZE];
    __shared__ int wsum[8];
    const int b = blockIdx.x;
    const int t = threadIdx.x;
    const int lane = t & 63;
    const int w = t >> 6;
    const int node0 = b << BSHIFT;
    const int nlocal = min(BSIZE, N - node0);
    const int pstart = b * BCAP;
    const int cnt = cur2[b] - pstart;
    const int base = bbase[b];

    if (t < BSIZE) h[t] = 0;
    __syncthreads();

    for (int e = t; e < cnt; e += 1024) {     // only global pairs read
        unsigned long long p = pairs[pstart + e];
        sp[e] = p;
        atomicAdd(&h[(int)(p >> 32)], 1);
    }
    __syncthreads();

    // scan h[0..511]: 8-wave shfl scan + cross-wave fixup
    int myh = (t < BSIZE) ? h[t] : 0;
    int s = myh;
#pragma unroll
    for (int d = 1; d < 64; d <<= 1) {
        int u = __shfl_up(s, d);
        if (lane >= d) s += u;
    }
    if (t < BSIZE && lane == 63) wsum[w] = s;
    __syncthreads();
    if (t == 0) {
        int run = 0;
#pragma unroll
        for (int i = 0; i < 8; i++) { int x = wsum[i]; wsum[i] = run; run += x; }
    }
    __syncthreads();
    if (t < BSIZE) {
        int excl = s + wsum[w] - myh;         // bucket-local exclusive prefix
        cur[t] = excl;
        if (t < nlocal) {
            off[node0 + t] = base + excl;
            dinv[node0 + t] = rsqrtf((float)(myh + 1));
        }
    }
    __syncthreads();

    for (int e = t; e < cnt; e += 1024) {     // LDS scatter
        unsigned long long p = sp[e];
        int pos = atomicAdd(&cur[(int)(p >> 32)], 1);
        cs[pos] = (int)(p & 0xffffffffu);
    }
    __syncthreads();

    for (int j = t; j < cnt; j += 1024)       // coalesced write-out
        csr[base + j] = cs[j];
}

// Fused GEMM via split-bf16 MFMA: out = post( pre(in) @ W )
//   pre(v)  = pre_flag ? relu(dinv[row]*v + b_pre[col]) : v
//   post(a) = (post_scale ? dinv[row]*a : a) + (b_post ? b_post[col] : 0)
// Block = 64 rows x 64 cols, 4 waves x 16 rows. Per wave:
//   A-frags: lane reads in[row0+(l&15)][kc*32+(l>>4)*8 ..+7] from global,
//            pre-transform in fp32, split to bf16 hi/lo (x = xh + xl).
//   B-frags: W staged transposed hi/lo in LDS; lane b128-reads
//            Wt[ct*16+(l&15)][kc*32+(l>>4)*8 ..+7].
//   acc[ct] += xh*wh + xl*wh + xh*wl + xl*wl  (4 MFMAs per (ct,kc))
//   => fp32-accurate GEMM at matrix-core rate.
__global__ __launch_bounds__(WG, 4) void gemm_fused(
    const float* __restrict__ in, const float* __restrict__ W,
    const float* __restrict__ dinv, const float* __restrict__ b_pre, int pre_flag,
    int post_scale, const float* __restrict__ b_post,
    void* __restrict__ out1, int out_bf16, int n_rows)
{
    __shared__ __align__(16) short Wh[64 * WT_LD];
    __shared__ __align__(16) short Wl[64 * WT_LD];

    const int t = threadIdx.x;

    // stage W transposed, split hi/lo bf16 (Wt[j][k], j = output col)
    const float4* W4 = (const float4*)W;
#pragma unroll
    for (int i = 0; i < 4; i++) {
        int q = i * WG + t;              // float4 index, 1024 total
        float4 w = W4[q];
        int base = q * 4;
        int k = base >> 6;
        int j0 = base & 63;
        float wf[4] = {w.x, w.y, w.z, w.w};
#pragma unroll
        for (int e = 0; e < 4; e++) {
            unsigned short h = f2bf(wf[e]);
            Wh[(j0 + e) * WT_LD + k] = (short)h;
            Wl[(j0 + e) * WT_LD + k] = (short)f2bf(wf[e] - bf2f(h));
        }
    }

    const int wid = t >> 6;              // wave 0..3
    const int l = t & 63;
    const int lr = l & 15;
    const int lk = l >> 4;
    const int row0 = blockIdx.x * 64 + wid * 16;
    const int arow = row0 + lr;
    const int srow = (arow < n_rows) ? arow : 0;   // safe row for loads

    // A fragments: 2 k-chunks of 32, pre-transform + hi/lo split
    bf16x8 ah[2], al[2];
    float dv = pre_flag ? dinv[srow] : 0.f;
#pragma unroll
    for (int kc = 0; kc < 2; kc++) {
        const float* p = in + (size_t)srow * 64 + kc * 32 + lk * 8;
        float4 v0 = *(const float4*)p;
        float4 v1 = *(const float4*)(p + 4);
        float vv[8] = {v0.x, v0.y, v0.z, v0.w, v1.x, v1.y, v1.z, v1.w};
        if (pre_flag) {
            const float* bp = b_pre + kc * 32 + lk * 8;
            float4 b0 = *(const float4*)bp;
            float4 b1 = *(const float4*)(bp + 4);
            float bb[8] = {b0.x, b0.y, b0.z, b0.w, b1.x, b1.y, b1.z, b1.w};
#pragma unroll
            for (int e = 0; e < 8; e++)
                vv[e] = fmaxf(fmaf(dv, vv[e], bb[e]), 0.f);
        }
#pragma unroll
        for (int e = 0; e < 8; e++) {
            unsigned short h = f2bf(vv[e]);
            ah[kc][e] = (short)h;
            al[kc][e] = (short)f2bf(vv[e] - bf2f(h));
        }
    }

    __syncthreads();

    f32x4 acc[4] = {};
#pragma unroll
    for (int ct = 0; ct < 4; ct++) {
#pragma unroll
        for (int kc = 0; kc < 2; kc++) {
            const short* ph = &Wh[(ct * 16 + lr) * WT_LD + kc * 32 + lk * 8];
            const short* pl = &Wl[(ct * 16 + lr) * WT_LD + kc * 32 + lk * 8];
            bf16x8 bh = *(const bf16x8*)ph;
            bf16x8 bl = *(const bf16x8*)pl;
            acc[ct] = __builtin_amdgcn_mfma_f32_16x16x32_bf16(ah[kc], bh, acc[ct], 0, 0, 0);
            acc[ct] = __builtin_amdgcn_mfma_f32_16x16x32_bf16(al[kc], bh, acc[ct], 0, 0, 0);
            acc[ct] = __builtin_amdgcn_mfma_f32_16x16x32_bf16(ah[kc], bl, acc[ct], 0, 0, 0);
            acc[ct] = __builtin_amdgcn_mfma_f32_16x16x32_bf16(al[kc], bl, acc[ct], 0, 0, 0);
        }
    }

    // store: D[row = row0 + lk*4 + r][col = ct*16 + lr]  (m89-verified C/D map)
#pragma unroll
    for (int r = 0; r < 4; r++) {
        int orow = row0 + lk * 4 + r;
        if (orow >= n_rows) continue;
        float sc = post_scale ? dinv[orow] : 1.0f;
#pragma unroll
        for (int ct = 0; ct < 4; ct++) {
            float bpv = b_post ? b_post[ct * 16 + lr] : 0.f;
            float o = fmaf(acc[ct][r], sc, bpv);
            if (out_bf16)
                ((unsigned short*)out1)[((size_t)orow << 6) + ct * 16 + lr] = f2bf(o);
            else
                ((float*)out1)[((size_t)orow << 6) + ct * 16 + lr] = o;
        }
    }
}

__device__ __forceinline__ void acc_bf16x2(float& a, float& b, unsigned u) {
    union { unsigned v; float f; } lo, hi;
    lo.v = u << 16;
    hi.v = u & 0xffff0000u;
    a += lo.f;
    b += hi.f;
}

// Segmented reduction over dst-CSR: B[d] = A[d] + sum A[csr[e]]  (A is bf16).
// Quarter-wave (16 lanes) per node: lane owns uint2 (4 bf16 cols) of the row,
// so no cross-lane combine and a direct float4 store (1KB/wave, coalesced).
// 4 nodes per wave run in the same instruction stream (exec-masked by their
// own degree); 16-deep unrolled edge loop keeps up to 16 gather loads in
// flight per wave. Indices prefetched 16/node and broadcast via shfl.
__global__ __launch_bounds__(WG) void aggregate(
    const uint2* __restrict__ A4, float* __restrict__ B,
    const int* __restrict__ off, const int* __restrict__ csr, int N)
{
    const int t = threadIdx.x;
    const int l = t & 63;
    const int c = l & 15;           // uint2 col (4 bf16 values)
    const int g = l >> 4;           // quarter-wave = node sub-slot
    const int gl = g << 4;
    int node = blockIdx.x * 16 + ((t >> 6) << 2) + g;
    const bool valid = node < N;
    if (!valid) node = N - 1;

    const int s0 = off[node];
    const int s1 = valid ? off[node + 1] : s0;

    uint2 v = A4[((size_t)node << 4) + c];          // self-loop row
    float4 acc = make_float4(0.f, 0.f, 0.f, 0.f);
    acc_bf16x2(acc.x, acc.y, v.x);
    acc_bf16x2(acc.z, acc.w, v.y);

    for (int p = s0; p < s1; p += 16) {
        const int cnt = min(16, s1 - p);
        int idx = (c < cnt) ? csr[p + c] : 0;       // 16-wide prefetch per node
#pragma unroll
        for (int k = 0; k < 16; k++) {
            int src = __shfl(idx, gl + k);          // broadcast within quarter
            if (k < cnt) {
                uint2 wv = A4[((size_t)src << 4) + c];
                acc_bf16x2(acc.x, acc.y, wv.x);
                acc_bf16x2(acc.z, acc.w, wv.y);
            }
        }
    }

    if (valid)
        *(float4*)(B + ((size_t)node << 6) + 4 * c) = acc;   // coalesced
}

extern "C" void kernel_launch(void* const* d_in, const int* in_sizes, int n_in,
                              void* d_out, int out_size, void* d_ws, size_t ws_size,
                              hipStream_t stream) {
    const float* x  = (const float*)d_in[0];
    const int*   ei = (const int*)d_in[1];
    const float* W1 = (const float*)d_in[2];
    const float* b1 = (const float*)d_in[3];
    const float* W2 = (const float*)d_in[4];
    const float* b2 = (const float*)d_in[5];
    const float* W3 = (const float*)d_in[6];
    const float* b3 = (const float*)d_in[7];
    float* out = (float*)d_out;

    const int N = in_sizes[0] / 64;    // 100000
    const int E = in_sizes[1] / 2;     // 1250000
    const int nbk = (N + BSIZE - 1) / BSIZE;        // 196 buckets

    // workspace layout
    int*   off  = (int*)d_ws;                       // N+1
    int*   csr  = off + (N + 1);                    // E
    int*   cur2 = csr + E;                          // 256
    int*   bbase= cur2 + 256;                       // 256
    uintptr_t pa = (uintptr_t)(bbase + 256);
    pa = (pa + 255) & ~(uintptr_t)255;
    float* dinv = (float*)pa;                       // N
    __hip_bfloat16* A = (__hip_bfloat16*)(dinv + N);// N*64 bf16 (hs)
    float* B    = (float*)(A + (size_t)N * 64);     // N*64 fp32 (agg)
    unsigned long long* pairs = (unsigned long long*)B;  // aliased: dead until agg1
                                                    // nbk*BCAP*8 = 12.9MB <= 25.6MB

    const int gG = (N + 63) / 64;
    const int gA = (N + 15) / 16;
    const int gP = (E + PCHUNK - 1) / PCHUNK;

    // CSR build (per call; ws re-poisoned every launch)
    bcur_init<<<1,   WG, 0, stream>>>(cur2, nbk);
    partition<<<gP,  WG, 0, stream>>>(ei, cur2, pairs, E);
    bsum_scan<<<1,   WG, 0, stream>>>(cur2, bbase, nbk, off, N);
    csr_local<<<nbk, 1024, 0, stream>>>(pairs, cur2, bbase, off, dinv, csr, N);

    // Layer 1: A = bf16(dinv.*(x@W1)); B = A[d] + sum A[src]
    gemm_fused<<<gG, WG, 0, stream>>>(x, W1, dinv, nullptr, 0, 1, nullptr, A, 1, N);
    aggregate <<<gA, WG, 0, stream>>>((const uint2*)A, B, off, csr, N);

    // Layer 2: in = B (pre: relu(dinv*v + b1)); A = bf16(dinv.*(h@W2)); B = agg
    gemm_fused<<<gG, WG, 0, stream>>>(B, W2, dinv, b1, 1, 1, nullptr, A, 1, N);
    aggregate <<<gA, WG, 0, stream>>>((const uint2*)A, B, off, csr, N);

    // Layer 3: in = B (pre: relu(dinv*v + b2)); out = h@W3 + b3 (fp32)
    gemm_fused<<<gG, WG, 0, stream>>>(B, W3, dinv, b2, 1, 0, b3, out, 0, N);
}